// Round 9
// baseline (142.213 us; speedup 1.0000x reference)
//
#include <hip/hip_runtime.h>
#include <cfloat>
#include <cmath>

// x[B,W,L], shapelets[N,L], cls_w[1,N], cls_b[1]
constexpr int B = 64;
constexpr int W = 256;
constexpr int N = 128;
constexpr int L = 64;
constexpr int NC = 16;        // window-chunks per batch element
constexpr int WPB = W / NC;   // 16 windows per block

// VALU-pipe cross-lane add (DPP) — stays off the DS pipe (R8 win).
// CTRL: 0xB1 = quad_perm xor1, 0x4E = quad_perm xor2,
//       0x141 = row_half_mirror (xor-4 class), 0x140 = row_mirror (xor-8).
template <int CTRL>
__device__ __forceinline__ float dpp_add(float v) {
  return v + __int_as_float(__builtin_amdgcn_update_dpp(
                 0, __float_as_int(v), CTRL, 0xF, 0xF, true));
}

// ---------------------------------------------------------------------------
// Fused kernel: grid = B*NC = 1024 blocks of 256.
// Main body (R8 layout, DS-minimal + DPP reduce):
//   oct = tid&7  -> eighth (8 floats) of each row owned by this lane
//   grp = tid>>3 -> thread holds eighth-rows of shapelets 4*grp..4*grp+3
//                   (8 named float4 = 32 VGPRs -> structurally spill-free)
//   per window: 2 ds_read_b128 -> 32 fma -> 12 DPP-adds (VALU pipe).
// Writes part[b][c][n] (plain float4 stores), then release-fence +
// atomicAdd(ctr[b]); the 16th arriver for b runs the head for that b:
// cross-chunk min -> +||s_n||^2 -> sqrt -> dot(cls_w) -> sigmoid -> out[b].
// Pattern (fence + device-scope atomic ctr + fence) validated in R4.
// ---------------------------------------------------------------------------
__global__ __launch_bounds__(256) void shapelet_fused_kernel(
    const float* __restrict__ x, const float* __restrict__ shp,
    const float* __restrict__ cls_w, const float* __restrict__ cls_b,
    float* __restrict__ part, unsigned* __restrict__ ctr,
    float* __restrict__ out) {
  __shared__ float xs[WPB * L];   // 4 KB
  __shared__ float xnorm_s[WPB];
  __shared__ unsigned last_flag;

  const int b = blockIdx.x >> 4;
  const int c = blockIdx.x & 15;
  const int tid = threadIdx.x;
  const int oct = tid & 7;
  const int grp = tid >> 3;
  const int n0 = grp * 4;

  // --- Stage x[b, c*16:(c+1)*16, :]: one float4/thread; ||x_w||^2 via a
  // 16-lane DPP reduction (16 float4 per window).
  {
    const float4* xg =
        (const float4*)(x + ((size_t)b * W + (size_t)c * WPB) * L);
    float4 v = xg[tid];
    ((float4*)xs)[tid] = v;
    float p = v.x * v.x + v.y * v.y + v.z * v.z + v.w * v.w;
    p = dpp_add<0xB1>(p);
    p = dpp_add<0x4E>(p);
    p = dpp_add<0x141>(p);
    p = dpp_add<0x140>(p);
    if ((tid & 15) == 0) xnorm_s[tid >> 4] = p;
  }

  // --- Eighth-rows of 4 shapelets: 8 NAMED float4 (32 VGPRs). No arrays.
  const float4* g0 = (const float4*)(shp + (size_t)(n0 + 0) * L + oct * 8);
  const float4* g1 = (const float4*)(shp + (size_t)(n0 + 1) * L + oct * 8);
  const float4* g2 = (const float4*)(shp + (size_t)(n0 + 2) * L + oct * 8);
  const float4* g3 = (const float4*)(shp + (size_t)(n0 + 3) * L + oct * 8);
  const float4 s0a = g0[0], s0b = g0[1];
  const float4 s1a = g1[0], s1b = g1[1];
  const float4 s2a = g2[0], s2b = g2[1];
  const float4 s3a = g3[0], s3b = g3[1];

  __syncthreads();

  // --- min over all 16 windows of (xnorm_w - 2*dot(x_w, s_n)).
  float best0 = FLT_MAX, best1 = FLT_MAX, best2 = FLT_MAX, best3 = FLT_MAX;
  for (int w = 0; w < WPB; ++w) {
    const float4* xr = (const float4*)(xs + (size_t)w * L + oct * 8);
    const float4 xa = xr[0];
    const float4 xb = xr[1];

    float d0 = xa.x * s0a.x + xa.y * s0a.y;
    float d1 = xa.x * s1a.x + xa.y * s1a.y;
    float d2 = xa.x * s2a.x + xa.y * s2a.y;
    float d3 = xa.x * s3a.x + xa.y * s3a.y;
    d0 = fmaf(xa.z, s0a.z, d0); d0 = fmaf(xa.w, s0a.w, d0);
    d1 = fmaf(xa.z, s1a.z, d1); d1 = fmaf(xa.w, s1a.w, d1);
    d2 = fmaf(xa.z, s2a.z, d2); d2 = fmaf(xa.w, s2a.w, d2);
    d3 = fmaf(xa.z, s3a.z, d3); d3 = fmaf(xa.w, s3a.w, d3);
    d0 = fmaf(xb.x, s0b.x, d0); d0 = fmaf(xb.y, s0b.y, d0);
    d1 = fmaf(xb.x, s1b.x, d1); d1 = fmaf(xb.y, s1b.y, d1);
    d2 = fmaf(xb.x, s2b.x, d2); d2 = fmaf(xb.y, s2b.y, d2);
    d3 = fmaf(xb.x, s3b.x, d3); d3 = fmaf(xb.w, s3b.w, d3);
    d0 = fmaf(xb.z, s0b.z, d0); d0 = fmaf(xb.w, s0b.w, d0);
    d1 = fmaf(xb.z, s1b.z, d1); d1 = fmaf(xb.w, s1b.w, d1);
    d2 = fmaf(xb.z, s2b.z, d2); d2 = fmaf(xb.w, s2b.w, d2);
    d3 = fmaf(xb.z, s3b.z, d3); d3 = fmaf(xb.w, s3b.w, d3);

    // 8-lane reduction per dot — pure VALU (DPP).
    d0 = dpp_add<0xB1>(d0);  d1 = dpp_add<0xB1>(d1);
    d2 = dpp_add<0xB1>(d2);  d3 = dpp_add<0xB1>(d3);
    d0 = dpp_add<0x4E>(d0);  d1 = dpp_add<0x4E>(d1);
    d2 = dpp_add<0x4E>(d2);  d3 = dpp_add<0x4E>(d3);
    d0 = dpp_add<0x141>(d0); d1 = dpp_add<0x141>(d1);
    d2 = dpp_add<0x141>(d2); d3 = dpp_add<0x141>(d3);

    const float xn = xnorm_s[w];
    best0 = fminf(best0, fmaf(-2.f, d0, xn));
    best1 = fminf(best1, fmaf(-2.f, d1, xn));
    best2 = fminf(best2, fmaf(-2.f, d2, xn));
    best3 = fminf(best3, fmaf(-2.f, d3, xn));
  }

  // --- oct-leader writes 4 consecutive shapelet mins as one float4 store.
  if (oct == 0) {
    float4 o;
    o.x = best0; o.y = best1; o.z = best2; o.w = best3;
    *(float4*)(part + ((size_t)b * NC + c) * N + n0) = o;
  }

  // --- Release + last-arriver detection for this b.
  __threadfence();
  if (tid == 0) {
    last_flag = (atomicAdd(&ctr[b], 1u) == (unsigned)(NC - 1)) ? 1u : 0u;
  }
  __syncthreads();
  if (last_flag == 0) return;
  __threadfence();  // acquire: other blocks' part writes now visible

  // ---------------- Head for this b (one block, 256 threads) --------------
  // t = hc*128 + n: thread handles chunks [hc*8, hc*8+8) of shapelet n.
  __shared__ float halfmin[2 * N];
  __shared__ float red[2];
  {
    const int n = tid & 127;
    const int hc = tid >> 7;
    const float* pb = part + (size_t)b * NC * N + n;
    const int cbase = hc * 8;
    float m = FLT_MAX;
#pragma unroll
    for (int cc = 0; cc < 8; ++cc) m = fminf(m, pb[(size_t)(cbase + cc) * N]);
    halfmin[hc * N + n] = m;
  }
  __syncthreads();

  float v = 0.f;
  if (tid < N) {
    const int n = tid;
    float m = fminf(halfmin[n], halfmin[N + n]);

    // ||s_n||^2 straight out of float4 loads (L2-hot), no arrays.
    float sn = 0.f;
    const float4* sg = (const float4*)(shp + (size_t)n * L);
#pragma unroll
    for (int i = 0; i < L / 4; ++i) {
      float4 q = sg[i];
      sn = fmaf(q.x, q.x, sn);
      sn = fmaf(q.y, q.y, sn);
      sn = fmaf(q.z, q.z, sn);
      sn = fmaf(q.w, q.w, sn);
    }
    float d2 = fmaxf(m + sn, 0.f);
    v = sqrtf(d2) * cls_w[n];
  }

  // Sum over 128 lanes (2 waves): wave shuffle reduce + LDS combine.
#pragma unroll
  for (int off = 32; off > 0; off >>= 1) v += __shfl_down(v, off, 64);
  if (tid < N && (tid & 63) == 0) red[tid >> 6] = v;
  __syncthreads();
  if (tid == 0) {
    float z = red[0] + red[1] + cls_b[0];
    out[b] = 1.0f / (1.0f + expf(-z));
  }
}

// ---------------------------------------------------------------------------
// Fallback two-kernel path (only if ws_size were implausibly small).
// ---------------------------------------------------------------------------
__global__ __launch_bounds__(256) void shapelet_min_kernel(
    const float* __restrict__ x, const float* __restrict__ shp,
    float* __restrict__ part) {
  __shared__ float xs[WPB * L];
  __shared__ float xnorm_s[WPB];
  const int b = blockIdx.x >> 4;
  const int c = blockIdx.x & 15;
  const int tid = threadIdx.x;
  const int half = tid & 1;
  const int n = tid >> 1;
  {
    const float4* xg =
        (const float4*)(x + ((size_t)b * W + (size_t)c * WPB) * L);
    float4 v = xg[tid];
    ((float4*)xs)[tid] = v;
    float p = v.x * v.x + v.y * v.y + v.z * v.z + v.w * v.w;
    p = dpp_add<0xB1>(p);
    p = dpp_add<0x4E>(p);
    p = dpp_add<0x141>(p);
    p = dpp_add<0x140>(p);
    if ((tid & 15) == 0) xnorm_s[tid >> 4] = p;
  }
  const float4* sg = (const float4*)(shp + (size_t)n * L + half * 32);
  const float4 s0 = sg[0], s1 = sg[1], s2 = sg[2], s3 = sg[3];
  const float4 s4 = sg[4], s5 = sg[5], s6 = sg[6], s7 = sg[7];
  __syncthreads();
  float best = FLT_MAX;
  for (int w = 0; w < WPB; ++w) {
    const float4* xr = (const float4*)(xs + (size_t)w * L + half * 32);
    float a0 = 0.f, a1 = 0.f, a2 = 0.f, a3 = 0.f;
#define SHP_STEP(K, SV)          \
  {                              \
    float4 xv = xr[K];           \
    a0 = fmaf(xv.x, (SV).x, a0); \
    a1 = fmaf(xv.y, (SV).y, a1); \
    a2 = fmaf(xv.z, (SV).z, a2); \
    a3 = fmaf(xv.w, (SV).w, a3); \
  }
    SHP_STEP(0, s0) SHP_STEP(1, s1) SHP_STEP(2, s2) SHP_STEP(3, s3)
    SHP_STEP(4, s4) SHP_STEP(5, s5) SHP_STEP(6, s6) SHP_STEP(7, s7)
#undef SHP_STEP
    float d = (a0 + a1) + (a2 + a3);
    d = dpp_add<0xB1>(d);
    best = fminf(best, fmaf(-2.f, d, xnorm_s[w]));
  }
  if (half == 0) part[((size_t)b * NC + c) * N + n] = best;
}

__global__ __launch_bounds__(128) void shapelet_head_kernel(
    const float* __restrict__ part, const float* __restrict__ shp,
    const float* __restrict__ cls_w, const float* __restrict__ cls_b,
    float* __restrict__ out) {
  const int b = blockIdx.x;
  const int n = threadIdx.x;
  float m = FLT_MAX;
#pragma unroll
  for (int c = 0; c < NC; ++c)
    m = fminf(m, part[((size_t)b * NC + c) * N + n]);
  float sn = 0.f;
  const float4* sg = (const float4*)(shp + (size_t)n * L);
#pragma unroll
  for (int i = 0; i < L / 4; ++i) {
    float4 v = sg[i];
    sn = fmaf(v.x, v.x, sn);
    sn = fmaf(v.y, v.y, sn);
    sn = fmaf(v.z, v.z, sn);
    sn = fmaf(v.w, v.w, sn);
  }
  float v = sqrtf(fmaxf(m + sn, 0.f)) * cls_w[n];
#pragma unroll
  for (int off = 32; off > 0; off >>= 1) v += __shfl_down(v, off, 64);
  __shared__ float red[2];
  if ((n & 63) == 0) red[n >> 6] = v;
  __syncthreads();
  if (n == 0) {
    float z = red[0] + red[1] + cls_b[0];
    out[b] = 1.0f / (1.0f + expf(-z));
  }
}

extern "C" void kernel_launch(void* const* d_in, const int* in_sizes, int n_in,
                              void* d_out, int out_size, void* d_ws,
                              size_t ws_size, hipStream_t stream) {
  const float* x = (const float*)d_in[0];      // [B, W, L]
  const float* shp = (const float*)d_in[1];    // [N, L]
  const float* cls_w = (const float*)d_in[2];  // [1, N]
  const float* cls_b = (const float*)d_in[3];  // [1]
  float* out = (float*)d_out;                  // [B, 1]

  const size_t part_elems = (size_t)B * NC * N;           // 131072 floats
  const size_t need = part_elems * 4 + B * sizeof(unsigned);
  if (ws_size >= need) {
    float* part = (float*)d_ws;
    unsigned* ctr = (unsigned*)((char*)d_ws + part_elems * 4);
    hipMemsetAsync(ctr, 0, B * sizeof(unsigned), stream);  // 256 B node
    shapelet_fused_kernel<<<B * NC, 256, 0, stream>>>(x, shp, cls_w, cls_b,
                                                      part, ctr, out);
  } else {
    float* part = (float*)d_ws;
    shapelet_min_kernel<<<B * NC, 256, 0, stream>>>(x, shp, part);
    shapelet_head_kernel<<<B, 128, 0, stream>>>(part, shp, cls_w, cls_b, out);
  }
}

// Round 10
// 69.384 us; speedup vs baseline: 2.0496x; 2.0496x over previous
//
#include <hip/hip_runtime.h>
#include <cfloat>
#include <cmath>

// x[B,W,L], shapelets[N,L], cls_w[1,N], cls_b[1]
constexpr int B = 64;
constexpr int W = 256;
constexpr int N = 128;
constexpr int L = 64;
constexpr int NC = 16;        // window-chunks per batch element
constexpr int WPB = W / NC;   // 16 windows per block

// VALU-pipe cross-lane add (DPP), avoiding the DS pipe entirely.
// CTRL: 0xB1 = quad_perm xor1, 0x4E = quad_perm xor2,
//       0x141 = row_half_mirror (xor-4 class), 0x140 = row_mirror (xor-8).
template <int CTRL>
__device__ __forceinline__ float dpp_add(float v) {
  return v + __int_as_float(__builtin_amdgcn_update_dpp(
                 0, __float_as_int(v), CTRL, 0xF, 0xF, true));
}

// ---------------------------------------------------------------------------
// Kernel 1: per-(b, chunk) compute  min_w ( ||x_w||^2 - 2 <x_w, s_n> )  for
// all 128 shapelets. ||s_n||^2 added in kernel 2 (min commutes with it).
// grid = B*NC, block = 256.
//
// R6/R7 post-mortem: the DS pipe is the bottleneck (~12 cyc per ds_read_b128
// per CU, and __shfl_* ALSO issue on the DS pipe). This version keeps DS
// traffic at 2 ds_read_b128 per window per thread and does ALL cross-lane
// reduction on the VALU pipe via DPP (quad_perm / row_half_mirror).
//   oct = tid&7  -> which eighth (8 floats) of each row this lane owns
//   grp = tid>>3 -> thread holds eighth-rows of shapelets 4*grp..4*grp+3
//                   (8 named float4 = 32 VGPRs -> structurally spill-free)
//
// R9 post-mortem (DO NOT REFUSE): appending a divergent last-block tail to
// this kernel made the register allocator under-budget (VGPR_Count=32) and
// spill the hot loop -> 95 us. Keep this kernel STANDALONE.
// ---------------------------------------------------------------------------
__global__ __launch_bounds__(256) void shapelet_min_kernel(
    const float* __restrict__ x, const float* __restrict__ shp,
    float* __restrict__ part) {
  __shared__ float xs[WPB * L];   // 4 KB
  __shared__ float xnorm_s[WPB];

  const int b = blockIdx.x >> 4;
  const int c = blockIdx.x & 15;
  const int tid = threadIdx.x;
  const int oct = tid & 7;        // eighth-of-row owned by this lane
  const int grp = tid >> 3;       // 0..31 -> shapelets 4*grp..4*grp+3
  const int n0 = grp * 4;

  // --- Stage x[b, c*16:(c+1)*16, :]: one float4/thread; ||x_w||^2 via a
  // 16-lane DPP reduction (16 float4 per window) — zero DS-pipe swizzles.
  {
    const float4* xg =
        (const float4*)(x + ((size_t)b * W + (size_t)c * WPB) * L);
    float4 v = xg[tid];
    ((float4*)xs)[tid] = v;
    float p = v.x * v.x + v.y * v.y + v.z * v.z + v.w * v.w;
    p = dpp_add<0xB1>(p);    // xor1 (quad)
    p = dpp_add<0x4E>(p);    // xor2 (quad)
    p = dpp_add<0x141>(p);   // 4<->8 within row of 16
    p = dpp_add<0x140>(p);   // mirror row of 16
    if ((tid & 15) == 0) xnorm_s[tid >> 4] = p;
  }

  // --- Eighth-rows of 4 shapelets: 8 NAMED float4 (32 VGPRs). No arrays.
  const float4* g0 = (const float4*)(shp + (size_t)(n0 + 0) * L + oct * 8);
  const float4* g1 = (const float4*)(shp + (size_t)(n0 + 1) * L + oct * 8);
  const float4* g2 = (const float4*)(shp + (size_t)(n0 + 2) * L + oct * 8);
  const float4* g3 = (const float4*)(shp + (size_t)(n0 + 3) * L + oct * 8);
  const float4 s0a = g0[0], s0b = g0[1];
  const float4 s1a = g1[0], s1b = g1[1];
  const float4 s2a = g2[0], s2b = g2[1];
  const float4 s3a = g3[0], s3b = g3[1];

  __syncthreads();

  // --- min over all 16 windows of (xnorm_w - 2*dot(x_w, s_n)).
  float best0 = FLT_MAX, best1 = FLT_MAX, best2 = FLT_MAX, best3 = FLT_MAX;
  for (int w = 0; w < WPB; ++w) {
    // 2 ds_read_b128 per thread per window — the only DS traffic here.
    const float4* xr = (const float4*)(xs + (size_t)w * L + oct * 8);
    const float4 xa = xr[0];
    const float4 xb = xr[1];

    float d0 = xa.x * s0a.x + xa.y * s0a.y;
    float d1 = xa.x * s1a.x + xa.y * s1a.y;
    float d2 = xa.x * s2a.x + xa.y * s2a.y;
    float d3 = xa.x * s3a.x + xa.y * s3a.y;
    d0 = fmaf(xa.z, s0a.z, d0); d0 = fmaf(xa.w, s0a.w, d0);
    d1 = fmaf(xa.z, s1a.z, d1); d1 = fmaf(xa.w, s1a.w, d1);
    d2 = fmaf(xa.z, s2a.z, d2); d2 = fmaf(xa.w, s2a.w, d2);
    d3 = fmaf(xa.z, s3a.z, d3); d3 = fmaf(xa.w, s3a.w, d3);
    d0 = fmaf(xb.x, s0b.x, d0); d0 = fmaf(xb.y, s0b.y, d0);
    d1 = fmaf(xb.x, s1b.x, d1); d1 = fmaf(xb.y, s1b.y, d1);
    d2 = fmaf(xb.x, s2b.x, d2); d2 = fmaf(xb.y, s2b.y, d2);
    d3 = fmaf(xb.x, s3b.x, d3); d3 = fmaf(xb.y, s3b.y, d3);
    d0 = fmaf(xb.z, s0b.z, d0); d0 = fmaf(xb.w, s0b.w, d0);
    d1 = fmaf(xb.z, s1b.z, d1); d1 = fmaf(xb.w, s1b.w, d1);
    d2 = fmaf(xb.z, s2b.z, d2); d2 = fmaf(xb.w, s2b.w, d2);
    d3 = fmaf(xb.z, s3b.z, d3); d3 = fmaf(xb.w, s3b.w, d3);

    // 8-lane reduction per dot — pure VALU (DPP), no DS-pipe swizzles.
    d0 = dpp_add<0xB1>(d0);  d1 = dpp_add<0xB1>(d1);
    d2 = dpp_add<0xB1>(d2);  d3 = dpp_add<0xB1>(d3);
    d0 = dpp_add<0x4E>(d0);  d1 = dpp_add<0x4E>(d1);
    d2 = dpp_add<0x4E>(d2);  d3 = dpp_add<0x4E>(d3);
    d0 = dpp_add<0x141>(d0); d1 = dpp_add<0x141>(d1);
    d2 = dpp_add<0x141>(d2); d3 = dpp_add<0x141>(d3);

    const float xn = xnorm_s[w];
    best0 = fminf(best0, fmaf(-2.f, d0, xn));
    best1 = fminf(best1, fmaf(-2.f, d1, xn));
    best2 = fminf(best2, fmaf(-2.f, d2, xn));
    best3 = fminf(best3, fmaf(-2.f, d3, xn));
  }

  // --- oct-leader writes 4 consecutive shapelet mins as one float4 store.
  if (oct == 0) {
    float4 o;
    o.x = best0; o.y = best1; o.z = best2; o.w = best3;
    *(float4*)(part + ((size_t)b * NC + c) * N + n0) = o;
  }
}

// ---------------------------------------------------------------------------
// Kernel 2: min over chunks -> +||s_n||^2 -> sqrt -> dot(cls_w) -> sigmoid.
// grid = B, block = 128 (one thread per shapelet). No allocas anywhere.
// ---------------------------------------------------------------------------
__global__ __launch_bounds__(128) void shapelet_head_kernel(
    const float* __restrict__ part, const float* __restrict__ shp,
    const float* __restrict__ cls_w, const float* __restrict__ cls_b,
    float* __restrict__ out) {
  const int b = blockIdx.x;
  const int n = threadIdx.x;  // 0..127

  float m = FLT_MAX;
#pragma unroll
  for (int c = 0; c < NC; ++c)
    m = fminf(m, part[((size_t)b * NC + c) * N + n]);

  // ||s_n||^2: accumulate straight out of float4 loads (no array).
  float sn = 0.f;
  {
    const float4* sg = (const float4*)(shp + (size_t)n * L);
#pragma unroll
    for (int i = 0; i < L / 4; ++i) {
      float4 v = sg[i];
      sn = fmaf(v.x, v.x, sn);
      sn = fmaf(v.y, v.y, sn);
      sn = fmaf(v.z, v.z, sn);
      sn = fmaf(v.w, v.w, sn);
    }
  }

  float d2 = fmaxf(m + sn, 0.f);  // guard fp rounding before sqrt
  float v = sqrtf(d2) * cls_w[n];

  // Sum over 128 threads: wave64 shuffle reduce, combine 2 waves via LDS.
#pragma unroll
  for (int off = 32; off > 0; off >>= 1) v += __shfl_down(v, off, 64);

  __shared__ float red[2];
  if ((n & 63) == 0) red[n >> 6] = v;
  __syncthreads();
  if (n == 0) {
    float z = red[0] + red[1] + cls_b[0];
    out[b] = 1.0f / (1.0f + expf(-z));
  }
}

extern "C" void kernel_launch(void* const* d_in, const int* in_sizes, int n_in,
                              void* d_out, int out_size, void* d_ws,
                              size_t ws_size, hipStream_t stream) {
  const float* x = (const float*)d_in[0];      // [B, W, L]
  const float* shp = (const float*)d_in[1];    // [N, L]
  const float* cls_w = (const float*)d_in[2];  // [1, N]
  const float* cls_b = (const float*)d_in[3];  // [1]
  float* out = (float*)d_out;                  // [B, 1]
  float* part = (float*)d_ws;                  // [B, NC, N] fp32 (128 KB)

  shapelet_min_kernel<<<B * NC, 256, 0, stream>>>(x, shp, part);
  shapelet_head_kernel<<<B, 128, 0, stream>>>(part, shp, cls_w, cls_b, out);
}